// Round 17
// baseline (326.710 us; speedup 1.0000x reference)
//
#include <hip/hip_runtime.h>

#define NN 250000
#define NE 8000000
#define NG 1024
#define FIN 16
#define HD 9
#define NSTAGE 64

#define CBIN 1024        // coarse bins
#define NPB 245          // nodes per bin (245*1024 = 250880 >= NN)
#define NBK 512          // chunk blocks (512*15625 = 8M exactly; longer runs -> less read amp)
#define EPB 15625        // NE / NBK
#define LOFFW 1025       // per-chunk local-offset row width (CBIN entries + total)
#define SCAP 9216        // LDS stage capacity per bin (mean 7813, sigma ~88)
#define NHALF 125000     // src-range split point (3MB hq slice per half -> L2-resident)
#define NKEY 512         // sort keys per bin: local*2 + srchalf (490 used)

static __device__ __forceinline__ float lrelu(float v) { return v > 0.f ? v : 0.2f * v; }

// RNE float->bf16 (low 16 bits of result)
static __device__ __forceinline__ unsigned f2bf(float f) {
    unsigned u = __float_as_uint(f);
    return (u + 0x7fffu + ((u >> 16) & 1u)) >> 16;
}
static __device__ __forceinline__ float bf_lo(unsigned u) { return __uint_as_float(u << 16); }
static __device__ __forceinline__ float bf_hi(unsigned u) { return __uint_as_float(u & 0xffff0000u); }

// exclusive prefix over 256 threads of v; optionally returns block total
static __device__ __forceinline__ int block_excl_scan(int v, int* total)
{
    int lane = threadIdx.x & 63, wv = threadIdx.x >> 6;
    int ps = v;
#pragma unroll
    for (int o = 1; o < 64; o <<= 1) { int u = __shfl_up(ps, o); if (lane >= o) ps += u; }
    __shared__ int wsum[4];
    if (lane == 63) wsum[wv] = ps;
    __syncthreads();
    int woff = 0;
    for (int w = 0; w < wv; w++) woff += wsum[w];
    if (total) *total = wsum[0] + wsum[1] + wsum[2] + wsum[3];
    __syncthreads();
    return woff + ps - v;
}

// ---------------- K1: LDS counting sort of each chunk by coarse bin (all writes coalesced) ----------------
__global__ void __launch_bounds__(256) chunk_sort(
    const int* __restrict__ srcs, const int* __restrict__ dsts,
    int* __restrict__ schunk, int* __restrict__ lrow)
{
    __shared__ int hist[CBIN];
    __shared__ int stage[EPB];
    int t = threadIdx.x, b = blockIdx.x;
    int base = b * EPB;
    int end = base + EPB; if (end > NE) end = NE;
    int n = end - base;
    for (int c = t; c < CBIN; c += 256) hist[c] = 0;
    __syncthreads();
    for (int e = base + t; e < end; e += 256)
        atomicAdd(&hist[(unsigned)dsts[e] / NPB], 1);
    __syncthreads();
    int v0 = hist[4*t], v1 = hist[4*t+1], v2 = hist[4*t+2], v3 = hist[4*t+3];
    int ex = block_excl_scan(v0 + v1 + v2 + v3, nullptr);   // syncs internally
    int e0 = ex, e1 = ex + v0, e2 = e1 + v1, e3 = e2 + v2;
    hist[4*t] = e0; hist[4*t+1] = e1; hist[4*t+2] = e2; hist[4*t+3] = e3;
    int* lr = lrow + (size_t)b * LOFFW;
    lr[4*t] = e0; lr[4*t+1] = e1; lr[4*t+2] = e2; lr[4*t+3] = e3;
    if (t == 255) lr[CBIN] = n;
    __syncthreads();
    for (int e = base + t; e < end; e += 256) {
        int src = srcs[e], dst = dsts[e];
        int bin = (unsigned)dst / NPB;
        int key = (dst - bin * NPB) * 2 + (src >= NHALF ? 1 : 0);
        int p = atomicAdd(&hist[bin], 1);
        stage[p] = (src << 9) | key;
    }
    __syncthreads();
    for (int i = t; i < n; i += 256) schunk[base + i] = stage[i];
}

// ---------------- K2a: per-bin scan over chunk run-lengths -> row-major coffT/rstartT ----------------
__global__ void __launch_bounds__(256) bin_scan_chunks(
    const int* __restrict__ lrow, int* __restrict__ coffT, int* __restrict__ rstartT,
    int* __restrict__ bintot)
{
    int bin = blockIdx.x, t = threadIdx.x;
    int v[2], st[2]; int sum = 0;
#pragma unroll
    for (int j = 0; j < 2; j++) {
        const int* lr = lrow + (size_t)(2 * t + j) * LOFFW + bin;
        st[j] = lr[0];
        v[j] = lr[1] - lr[0];
        sum += v[j];
    }
    int tot;
    int ex = block_excl_scan(sum, &tot);
    int run = ex;
    int* co = coffT + (size_t)bin * (NBK + 1);
    int* rs = rstartT + (size_t)bin * NBK;
#pragma unroll
    for (int j = 0; j < 2; j++) {
        co[2 * t + j] = run;
        rs[2 * t + j] = st[j];
        run += v[j];
    }
    if (t == 0) bintot[bin] = tot;
    if (t == 255) co[NBK] = run;
}

// ---------------- K2b: exclusive scan over bin totals -> binbase[CBIN+1] ----------------
__global__ void __launch_bounds__(256) bin_scan_bins(const int* __restrict__ bintot, int* __restrict__ binbase)
{
    int t = threadIdx.x;
    int i0 = 4 * t;
    int v0 = bintot[i0], v1 = bintot[i0 + 1], v2 = bintot[i0 + 2], v3 = bintot[i0 + 3];
    int ex = block_excl_scan(v0 + v1 + v2 + v3, nullptr);
    binbase[i0] = ex; binbase[i0 + 1] = ex + v0;
    binbase[i0 + 2] = ex + v0 + v1; binbase[i0 + 3] = ex + v0 + v1 + v2;
    if (t == 255) binbase[CBIN] = ex + v0 + v1 + v2 + v3;
}

// ---------------- K3: fused run-copy + per-bin counting sort over (node,srchalf) keys ----------------
// Serial per-thread run copy (compiler pipelines independent runs),
// LDS stageB scatter, coalesced global writeout.
__global__ void __launch_bounds__(256) bin_build(
    const int* __restrict__ schunk, const int* __restrict__ coffT, const int* __restrict__ rstartT,
    const int* __restrict__ binbase, int* __restrict__ binned, int* __restrict__ off2)
{
    __shared__ int stageA[SCAP];
    __shared__ int stageB[SCAP];
    __shared__ int cntS[NKEY];
    int bin = blockIdx.x, t = threadIdx.x;
    int beg = binbase[bin];
    int n = binbase[bin + 1] - beg; if (n > SCAP) n = SCAP;
    const int* co = coffT + (size_t)bin * (NBK + 1);
    const int* rs = rstartT + (size_t)bin * NBK;
    // gather this bin's 512 runs from sorted chunks into stageA at deterministic offsets
    for (int c = t; c < NBK; c += 256) {
        int o = co[c], len = co[c + 1] - o;
        const int* sp = schunk + (size_t)c * EPB + rs[c];
        for (int j = 0; j < len; j++)
            if (o + j < SCAP) stageA[o + j] = sp[j];
    }
    cntS[t] = 0; cntS[t + 256] = 0;
    __syncthreads();
    for (int i = t; i < n; i += 256)
        atomicAdd(&cntS[stageA[i] & (NKEY - 1)], 1);
    __syncthreads();
    // scan over 512 keys: thread t owns keys 2t (half 0), 2t+1 (half 1)
    int v0 = cntS[2 * t], v1 = cntS[2 * t + 1];
    int ex = block_excl_scan(v0 + v1, nullptr);
    {
        long long node0 = (long long)bin * NPB + t;
        if (t < NPB && node0 <= NN) {
            off2[2 * node0] = beg + ex;
            if (node0 < NN) off2[2 * node0 + 1] = beg + ex + v0;
        }
    }
    cntS[2 * t] = ex; cntS[2 * t + 1] = ex + v0;
    __syncthreads();
    for (int i = t; i < n; i += 256) {
        int rec = stageA[i];
        int p = atomicAdd(&cntS[rec & (NKEY - 1)], 1);
        if (p < SCAP) stageB[p] = rec >> 9;
    }
    __syncthreads();
    for (int i = t; i < n; i += 256) binned[beg + i] = stageB[i];
}

// ---------------- Layer-1 node prep: h = x@W (bf16-packed row + fp32 asrc), self-loop init ----------------
__global__ void __launch_bounds__(256) node_prep1(
    const float* __restrict__ x, const float* __restrict__ W,
    const float* __restrict__ as_, const float* __restrict__ ad_,
    uint2* __restrict__ hq, float* __restrict__ adst,
    float* __restrict__ s, float* __restrict__ acc)
{
    __shared__ float sW[FIN * HD];
    __shared__ float sas[HD], sad[HD];
    for (int t = threadIdx.x; t < FIN * HD; t += 256) sW[t] = W[t];
    if (threadIdx.x < HD) { sas[threadIdx.x] = as_[threadIdx.x]; sad[threadIdx.x] = ad_[threadIdx.x]; }
    __syncthreads();
    int i = blockIdx.x * 256 + threadIdx.x;
    if (i >= NN) return;
    float xi[FIN];
    const float4* xp = reinterpret_cast<const float4*>(x + (size_t)i * FIN);
#pragma unroll
    for (int q = 0; q < 4; q++) { float4 v = xp[q]; xi[4*q] = v.x; xi[4*q+1] = v.y; xi[4*q+2] = v.z; xi[4*q+3] = v.w; }
    float hv[HD];
#pragma unroll
    for (int k = 0; k < HD; k++) {
        float a = 0.f;
#pragma unroll
        for (int j = 0; j < FIN; j++) a = fmaf(xi[j], sW[j * HD + k], a);
        hv[k] = a;
    }
    float sa = 0.f, sd = 0.f;
#pragma unroll
    for (int k = 0; k < HD; k++) { sa = fmaf(hv[k], sas[k], sa); sd = fmaf(hv[k], sad[k], sd); }
    float w = __expf(lrelu(sa + sd));   // self-loop weight (exact softmax max-shift cancellation)
    adst[i] = sd; s[i] = w;
    uint2* hp = hq + (size_t)i * 3;
    hp[0] = make_uint2(f2bf(hv[0]) | (f2bf(hv[1]) << 16), f2bf(hv[2]) | (f2bf(hv[3]) << 16));
    hp[1] = make_uint2(f2bf(hv[4]) | (f2bf(hv[5]) << 16), f2bf(hv[6]) | (f2bf(hv[7]) << 16));
    hp[2] = make_uint2(f2bf(hv[8]), __float_as_uint(sa));
#pragma unroll
    for (int k = 0; k < HD; k++) acc[(size_t)i*HD+k] = w * hv[k];
}

// ---------------- Layer-2 node prep: recompute y1, BN affine, h2 = y@W2 (bf16 pack) ----------------
__global__ void __launch_bounds__(256) node_prep2(
    const float* __restrict__ accin, const float* __restrict__ sin, const float* __restrict__ b,
    const float* __restrict__ sc, const float* __restrict__ sh,
    const float* __restrict__ W, const float* __restrict__ as_, const float* __restrict__ ad_,
    uint2* __restrict__ hq, float* __restrict__ adst,
    float* __restrict__ s, float* __restrict__ acc)
{
    __shared__ float sW[HD * HD];
    __shared__ float sas[HD], sad[HD], ssc[HD], ssh[HD], sb[HD];
    for (int t = threadIdx.x; t < HD * HD; t += 256) sW[t] = W[t];
    if (threadIdx.x < HD) {
        sas[threadIdx.x] = as_[threadIdx.x]; sad[threadIdx.x] = ad_[threadIdx.x];
        ssc[threadIdx.x] = sc[threadIdx.x]; ssh[threadIdx.x] = sh[threadIdx.x];
        sb[threadIdx.x] = b[threadIdx.x];
    }
    __syncthreads();
    int i = blockIdx.x * 256 + threadIdx.x;
    if (i >= NN) return;
    float inv = 1.0f / (sin[i] + 1e-16f);
    float xi[HD];
#pragma unroll
    for (int k = 0; k < HD; k++) {
        float v = fmaf(accin[(size_t)i*HD+k], inv, sb[k]);
        v = v > 0.f ? v : 0.f;
        xi[k] = fmaf(v, ssc[k], ssh[k]);
    }
    float hv[HD];
#pragma unroll
    for (int k = 0; k < HD; k++) {
        float a = 0.f;
#pragma unroll
        for (int j = 0; j < HD; j++) a = fmaf(xi[j], sW[j * HD + k], a);
        hv[k] = a;
    }
    float sa = 0.f, sd = 0.f;
#pragma unroll
    for (int k = 0; k < HD; k++) { sa = fmaf(hv[k], sas[k], sa); sd = fmaf(hv[k], sad[k], sd); }
    float w = __expf(lrelu(sa + sd));
    adst[i] = sd; s[i] = w;
    uint2* hp = hq + (size_t)i * 3;
    hp[0] = make_uint2(f2bf(hv[0]) | (f2bf(hv[1]) << 16), f2bf(hv[2]) | (f2bf(hv[3]) << 16));
    hp[1] = make_uint2(f2bf(hv[4]) | (f2bf(hv[5]) << 16), f2bf(hv[6]) | (f2bf(hv[7]) << 16));
    hp[2] = make_uint2(f2bf(hv[8]), __float_as_uint(sa));
#pragma unroll
    for (int k = 0; k < HD; k++) acc[(size_t)i*HD+k] = w * hv[k];
}

// ---------------- Gather pass (per src-half): 8 lanes/node, 2x-unrolled, register accumulate ----------------
#define ACCUM(w, A, B, C) \
    a[0] = fmaf(w, bf_lo(A.x), a[0]); a[1] = fmaf(w, bf_hi(A.x), a[1]); \
    a[2] = fmaf(w, bf_lo(A.y), a[2]); a[3] = fmaf(w, bf_hi(A.y), a[3]); \
    a[4] = fmaf(w, bf_lo(B.x), a[4]); a[5] = fmaf(w, bf_hi(B.x), a[5]); \
    a[6] = fmaf(w, bf_lo(B.y), a[6]); a[7] = fmaf(w, bf_hi(B.y), a[7]); \
    a[8] = fmaf(w, bf_lo(C.x), a[8]);

__global__ void __launch_bounds__(256) gat_gather(
    const int* __restrict__ off2, const int* __restrict__ esrc,
    const uint2* __restrict__ hq, const float* __restrict__ adst,
    float* __restrict__ s, float* __restrict__ acc, int half)
{
    int gidx = blockIdx.x * 32 + (threadIdx.x >> 3);
    int lane = threadIdx.x & 7;
    if (gidx >= NN) return;
    int beg = off2[2 * gidx + half], end = off2[2 * gidx + half + 1];
    float ad = adst[gidx];
    float wsum = 0.f;
    float a[HD];
#pragma unroll
    for (int k = 0; k < HD; k++) a[k] = 0.f;
    int e = beg + lane;
    for (; e + 8 < end; e += 16) {
        int s0 = esrc[e], s1 = esrc[e + 8];
        const uint2* p0 = hq + (size_t)s0 * 3;
        const uint2* p1 = hq + (size_t)s1 * 3;
        uint2 A0 = p0[0], B0 = p0[1], C0 = p0[2];
        uint2 A1 = p1[0], B1 = p1[1], C1 = p1[2];
        float w0 = __expf(lrelu(__uint_as_float(C0.y) + ad));
        float w1 = __expf(lrelu(__uint_as_float(C1.y) + ad));
        wsum += w0 + w1;
        ACCUM(w0, A0, B0, C0);
        ACCUM(w1, A1, B1, C1);
    }
    if (e < end) {
        int s0 = esrc[e];
        const uint2* p0 = hq + (size_t)s0 * 3;
        uint2 A0 = p0[0], B0 = p0[1], C0 = p0[2];
        float w0 = __expf(lrelu(__uint_as_float(C0.y) + ad));
        wsum += w0;
        ACCUM(w0, A0, B0, C0);
    }
#pragma unroll
    for (int o = 1; o < 8; o <<= 1) {
        wsum += __shfl_xor(wsum, o);
#pragma unroll
        for (int k = 0; k < HD; k++) a[k] += __shfl_xor(a[k], o);
    }
    if (lane == 0) {
        s[gidx] += wsum;
        float* ap = acc + (size_t)gidx * HD;
#pragma unroll
        for (int k = 0; k < HD; k++) ap[k] += a[k];
    }
}

// ---------------- Layer-1 finish: BN stats (hierarchical, staged atomics) ----------------
__global__ void __launch_bounds__(256) node_finish1(
    const float* __restrict__ acc, const float* __restrict__ s, const float* __restrict__ b,
    float* __restrict__ stage)
{
    int i = blockIdx.x * 256 + threadIdx.x;
    bool act = i < NN;
    float inv = act ? 1.0f / (s[i] + 1e-16f) : 0.f;
    float y[HD];
#pragma unroll
    for (int k = 0; k < HD; k++) {
        float v = act ? fmaf(acc[(size_t)i*HD+k], inv, __ldg(&b[k])) : 0.f;
        y[k] = v > 0.f ? v : 0.f;
    }
    __shared__ float red[4][2 * HD];
    int lane = threadIdx.x & 63, wv = threadIdx.x >> 6;
#pragma unroll
    for (int k = 0; k < HD; k++) {
        float sm = y[k], sq = y[k] * y[k];
#pragma unroll
        for (int o = 32; o > 0; o >>= 1) { sm += __shfl_down(sm, o); sq += __shfl_down(sq, o); }
        if (lane == 0) { red[wv][k] = sm; red[wv][HD + k] = sq; }
    }
    __syncthreads();
    int t = threadIdx.x;
    if (t < 2 * HD) {
        float v = red[0][t] + red[1][t] + red[2][t] + red[3][t];
        atomicAdd(&stage[(blockIdx.x & (NSTAGE - 1)) * 2 * HD + t], v);
    }
}

// ---------------- Layer-2 finish: BN stats (staged) + wave-segmented pooling ----------------
__global__ void __launch_bounds__(256) node_finish2(
    const float* __restrict__ acc, const float* __restrict__ s, const float* __restrict__ b,
    const int* __restrict__ batch,
    float* __restrict__ stage,
    float* __restrict__ pool, float* __restrict__ cnt)
{
    int i = blockIdx.x * 256 + threadIdx.x;
    bool act = i < NN;
    float inv = act ? 1.0f / (s[i] + 1e-16f) : 0.f;
    float y[HD];
#pragma unroll
    for (int k = 0; k < HD; k++) {
        float v = act ? fmaf(acc[(size_t)i*HD+k], inv, __ldg(&b[k])) : 0.f;
        y[k] = v > 0.f ? v : 0.f;
    }
    __shared__ float red[4][2 * HD];
    int lane = threadIdx.x & 63, wv = threadIdx.x >> 6;
#pragma unroll
    for (int k = 0; k < HD; k++) {
        float sm = y[k], sq = y[k] * y[k];
#pragma unroll
        for (int o = 32; o > 0; o >>= 1) { sm += __shfl_down(sm, o); sq += __shfl_down(sq, o); }
        if (lane == 0) { red[wv][k] = sm; red[wv][HD + k] = sq; }
    }
    __syncthreads();
    int t = threadIdx.x;
    if (t < 2 * HD) {
        float v = red[0][t] + red[1][t] + red[2][t] + red[3][t];
        atomicAdd(&stage[(blockIdx.x & (NSTAGE - 1)) * 2 * HD + t], v);
    }
    // Wave-segmented pooling: one iteration per distinct graph in the wave.
    int g = act ? batch[i] : -1;
    unsigned long long alive = __ballot(g >= 0);
    while (alive) {
        int leader = (int)__builtin_ctzll(alive);
        int g0 = __shfl(g, leader);
        bool mine = (g == g0);
#pragma unroll
        for (int k = 0; k < HD; k++) {
            float v = mine ? y[k] : 0.f;
#pragma unroll
            for (int o = 32; o > 0; o >>= 1) v += __shfl_xor(v, o);
            if (lane == leader) atomicAdd(&pool[g0 * HD + k], v);
        }
        float c = mine ? 1.f : 0.f;
#pragma unroll
        for (int o = 32; o > 0; o >>= 1) c += __shfl_xor(c, o);
        if (lane == leader) atomicAdd(&cnt[g0], c);
        alive &= ~__ballot(mine);
    }
}

// ---------------- BN stat finalize ----------------
__global__ void bn_finalize(const float* __restrict__ stage,
                            const float* __restrict__ gamma, const float* __restrict__ beta,
                            float* __restrict__ scale, float* __restrict__ shift)
{
    __shared__ float tot[2 * HD];
    int t = threadIdx.x;
    if (t < 2 * HD) {
        float v = 0.f;
        for (int j = 0; j < NSTAGE; j++) v += stage[j * 2 * HD + t];
        tot[t] = v;
    }
    __syncthreads();
    if (t < HD) {
        float mu = tot[t] * (1.0f / NN);
        float var = tot[HD + t] * (1.0f / NN) - mu * mu;
        float rstd = rsqrtf(var + 1e-5f);
        float sc = gamma[t] * rstd;
        scale[t] = sc;
        shift[t] = beta[t] - mu * sc;
    }
}

// ---------------- Final: per-graph BN-affine + 4-layer linear MLP ----------------
__global__ void __launch_bounds__(256) final_mlp(
    const float* __restrict__ pool, const float* __restrict__ cnt,
    const float* __restrict__ sc, const float* __restrict__ sh,
    const float* __restrict__ mW1, const float* __restrict__ mb1,
    const float* __restrict__ mW2, const float* __restrict__ mb2,
    const float* __restrict__ mW3, const float* __restrict__ mb3,
    const float* __restrict__ mW4, const float* __restrict__ mb4,
    float* __restrict__ out)
{
    __shared__ float w1[81], w2[81], w3[81], bb1[9], bb2[9], bb3[9], w4[9], ssc[9], ssh[9];
    int t = threadIdx.x;
    if (t < 81) { w1[t] = mW1[t]; w2[t] = mW2[t]; w3[t] = mW3[t]; }
    if (t < 9) {
        bb1[t] = mb1[t]; bb2[t] = mb2[t]; bb3[t] = mb3[t];
        w4[t] = mW4[t]; ssc[t] = sc[t]; ssh[t] = sh[t];
    }
    __syncthreads();
    int g = blockIdx.x * 256 + t;
    if (g >= NG) return;
    float c = cnt[g];
    float p[9], q[9];
#pragma unroll
    for (int k = 0; k < 9; k++) p[k] = fmaf(ssc[k], pool[g * 9 + k], ssh[k] * c);
#pragma unroll
    for (int k = 0; k < 9; k++) {
        float a = bb1[k];
#pragma unroll
        for (int j = 0; j < 9; j++) a = fmaf(p[j], w1[j * 9 + k], a);
        q[k] = a;
    }
#pragma unroll
    for (int k = 0; k < 9; k++) {
        float a = bb2[k];
#pragma unroll
        for (int j = 0; j < 9; j++) a = fmaf(q[j], w2[j * 9 + k], a);
        p[k] = a;
    }
#pragma unroll
    for (int k = 0; k < 9; k++) {
        float a = bb3[k];
#pragma unroll
        for (int j = 0; j < 9; j++) a = fmaf(p[j], w3[j * 9 + k], a);
        q[k] = a;
    }
    float o = mb4[0];
#pragma unroll
    for (int j = 0; j < 9; j++) o = fmaf(q[j], w4[j], o);
    out[g] = o;
}

extern "C" void kernel_launch(void* const* d_in, const int* in_sizes, int n_in,
                              void* d_out, int out_size, void* d_ws, size_t ws_size,
                              hipStream_t stream)
{
    const float* x   = (const float*)d_in[0];
    const int*   ei  = (const int*)d_in[1];
    const int*   bat = (const int*)d_in[2];
    const float* W1  = (const float*)d_in[3];
    const float* as1 = (const float*)d_in[4];
    const float* ad1 = (const float*)d_in[5];
    const float* b1  = (const float*)d_in[6];
    const float* g1  = (const float*)d_in[7];
    const float* be1 = (const float*)d_in[8];
    const float* W2  = (const float*)d_in[9];
    const float* as2 = (const float*)d_in[10];
    const float* ad2 = (const float*)d_in[11];
    const float* b2  = (const float*)d_in[12];
    const float* g2  = (const float*)d_in[13];
    const float* be2 = (const float*)d_in[14];
    const float* mW1 = (const float*)d_in[15];
    const float* mb1 = (const float*)d_in[16];
    const float* mW2 = (const float*)d_in[17];
    const float* mb2 = (const float*)d_in[18];
    const float* mW3 = (const float*)d_in[19];
    const float* mb3 = (const float*)d_in[20];
    const float* mW4 = (const float*)d_in[21];
    const float* mb4 = (const float*)d_in[22];
    float* out = (float*)d_out;

    // -------- workspace layout (build-time buffers overlaid with layer-time buffers) --------
    float* ws   = (float*)d_ws;
    float* zb   = ws;                          // zeroed block (small, persistent)
    float* stg1 = zb;                          // 64*18
    float* stg2 = stg1 + NSTAGE * 2 * HD;      // 64*18
    float* pool = stg2 + NSTAGE * 2 * HD;      // G*9
    float* cnt  = pool + (size_t)NG * HD;      // G
    float* sc1  = cnt + NG;                    // 9
    float* sh1  = sc1 + HD;                    // 9
    float* sc2  = sh1 + HD;                    // 9
    float* sh2  = sc2 + HD;                    // 9
    int*   off2   = (int*)(sh2 + HD);          // 2*NN+1 (per-(node,srchalf) offsets)
    int*   binned = off2 + (2 * NN + 1);       // NE (node-half-sorted esrc)
    int*   uni    = binned + NE;               // union region: schunk (NE ints) | {hq,adst,s,acc}
    int*   schunk = uni;                       // NE ints (sorted chunks; dead after bin_build)
    uint2* hq     = (uint2*)uni;               // NN rows x 24B = 1.5M words (overlays schunk)
    float* adst   = (float*)uni + (size_t)NN * 6;  // N
    float* s      = adst + NN;                 // N
    float* acc    = s + NN;                    // N*9  (total 4.25M words < NE=8M ✓)
    int*   lrow    = uni + NE;                 // NBK*LOFFW
    int*   coffT   = lrow + (size_t)NBK * LOFFW;        // CBIN*(NBK+1) row-major
    int*   rstartT = coffT + (size_t)CBIN * (NBK + 1);  // CBIN*NBK row-major
    int*   bintot  = rstartT + (size_t)CBIN * NBK;      // CBIN
    int*   binbase = bintot + CBIN;            // CBIN+1

    size_t zbytes = (size_t)(2 * NSTAGE * 2 * HD + NG * HD + NG + 4 * HD) * sizeof(float);
    hipMemsetAsync(zb, 0, zbytes, stream);

    const int* srcs = ei;
    const int* dsts = ei + NE;
    int nb  = (NN + 255) / 256;
    int ngb = (NN + 31) / 32;

    // CSR build: LDS chunk sort -> scans (row-major metadata) -> fused run-copy + (node,half) sort
    chunk_sort<<<NBK, 256, 0, stream>>>(srcs, dsts, schunk, lrow);
    bin_scan_chunks<<<CBIN, 256, 0, stream>>>(lrow, coffT, rstartT, bintot);
    bin_scan_bins<<<1, 256, 0, stream>>>(bintot, binbase);
    bin_build<<<CBIN, 256, 0, stream>>>(schunk, coffT, rstartT, binbase, binned, off2);

    // Layer 1 (hq overwrites dead schunk region); two gather passes, each an L2-resident hq slice
    node_prep1<<<nb, 256, 0, stream>>>(x, W1, as1, ad1, hq, adst, s, acc);
    gat_gather<<<ngb, 256, 0, stream>>>(off2, binned, hq, adst, s, acc, 0);
    gat_gather<<<ngb, 256, 0, stream>>>(off2, binned, hq, adst, s, acc, 1);
    node_finish1<<<nb, 256, 0, stream>>>(acc, s, b1, stg1);
    bn_finalize<<<1, 64, 0, stream>>>(stg1, g1, be1, sc1, sh1);

    // Layer 2
    node_prep2<<<nb, 256, 0, stream>>>(acc, s, b1, sc1, sh1, W2, as2, ad2, hq, adst, s, acc);
    gat_gather<<<ngb, 256, 0, stream>>>(off2, binned, hq, adst, s, acc, 0);
    gat_gather<<<ngb, 256, 0, stream>>>(off2, binned, hq, adst, s, acc, 1);
    node_finish2<<<nb, 256, 0, stream>>>(acc, s, b2, bat, stg2, pool, cnt);
    bn_finalize<<<1, 64, 0, stream>>>(stg2, g2, be2, sc2, sh2);

    final_mlp<<<(NG + 255) / 256, 256, 0, stream>>>(pool, cnt, sc2, sh2,
                                                    mW1, mb1, mW2, mb2, mW3, mb3, mW4, mb4, out);
}

// Round 18
// 317.975 us; speedup vs baseline: 1.0275x; 1.0275x over previous
//
#include <hip/hip_runtime.h>

#define NN 250000
#define NE 8000000
#define NG 1024
#define FIN 16
#define HD 9
#define NSTAGE 64

#define CBIN 1024        // coarse bins
#define NPB 245          // nodes per bin (245*1024 = 250880 >= NN)
#define NBK 1024         // chunk blocks (best measured config: 4 blocks/CU in chunk_sort)
#define EPB 7813         // ceil(NE/NBK); 1024*7813 = 8000512 (last chunk partial)
#define LOFFW 1025       // per-chunk local-offset row width (CBIN entries + total)
#define SCAP 9216        // LDS stage capacity per bin (mean 7840, sigma ~89)
#define NHALF 125000     // src-range split point (3MB hq slice per half -> L2-resident)
#define NKEY 512         // sort keys per bin: local*2 + srchalf (490 used)

static __device__ __forceinline__ float lrelu(float v) { return v > 0.f ? v : 0.2f * v; }

// RNE float->bf16 (low 16 bits of result)
static __device__ __forceinline__ unsigned f2bf(float f) {
    unsigned u = __float_as_uint(f);
    return (u + 0x7fffu + ((u >> 16) & 1u)) >> 16;
}
static __device__ __forceinline__ float bf_lo(unsigned u) { return __uint_as_float(u << 16); }
static __device__ __forceinline__ float bf_hi(unsigned u) { return __uint_as_float(u & 0xffff0000u); }

// exclusive prefix over 256 threads of v; optionally returns block total
static __device__ __forceinline__ int block_excl_scan(int v, int* total)
{
    int lane = threadIdx.x & 63, wv = threadIdx.x >> 6;
    int ps = v;
#pragma unroll
    for (int o = 1; o < 64; o <<= 1) { int u = __shfl_up(ps, o); if (lane >= o) ps += u; }
    __shared__ int wsum[4];
    if (lane == 63) wsum[wv] = ps;
    __syncthreads();
    int woff = 0;
    for (int w = 0; w < wv; w++) woff += wsum[w];
    if (total) *total = wsum[0] + wsum[1] + wsum[2] + wsum[3];
    __syncthreads();
    return woff + ps - v;
}

// ---------------- K1: LDS counting sort of each chunk by coarse bin (all writes coalesced) ----------------
__global__ void __launch_bounds__(256) chunk_sort(
    const int* __restrict__ srcs, const int* __restrict__ dsts,
    int* __restrict__ schunk, int* __restrict__ lrow)
{
    __shared__ int hist[CBIN];
    __shared__ int stage[EPB];
    int t = threadIdx.x, b = blockIdx.x;
    int base = b * EPB;
    int end = base + EPB; if (end > NE) end = NE;
    int n = end - base;
    for (int c = t; c < CBIN; c += 256) hist[c] = 0;
    __syncthreads();
    for (int e = base + t; e < end; e += 256)
        atomicAdd(&hist[(unsigned)dsts[e] / NPB], 1);
    __syncthreads();
    int v0 = hist[4*t], v1 = hist[4*t+1], v2 = hist[4*t+2], v3 = hist[4*t+3];
    int ex = block_excl_scan(v0 + v1 + v2 + v3, nullptr);   // syncs internally
    int e0 = ex, e1 = ex + v0, e2 = e1 + v1, e3 = e2 + v2;
    hist[4*t] = e0; hist[4*t+1] = e1; hist[4*t+2] = e2; hist[4*t+3] = e3;
    int* lr = lrow + (size_t)b * LOFFW;
    lr[4*t] = e0; lr[4*t+1] = e1; lr[4*t+2] = e2; lr[4*t+3] = e3;
    if (t == 255) lr[CBIN] = n;
    __syncthreads();
    for (int e = base + t; e < end; e += 256) {
        int src = srcs[e], dst = dsts[e];
        int bin = (unsigned)dst / NPB;
        int key = (dst - bin * NPB) * 2 + (src >= NHALF ? 1 : 0);
        int p = atomicAdd(&hist[bin], 1);
        stage[p] = (src << 9) | key;
    }
    __syncthreads();
    for (int i = t; i < n; i += 256) schunk[base + i] = stage[i];
}

// ---------------- K2a: per-bin scan over chunk run-lengths -> row-major coffT/rstartT ----------------
__global__ void __launch_bounds__(256) bin_scan_chunks(
    const int* __restrict__ lrow, int* __restrict__ coffT, int* __restrict__ rstartT,
    int* __restrict__ bintot)
{
    int bin = blockIdx.x, t = threadIdx.x;
    int v[4], st[4]; int sum = 0;
#pragma unroll
    for (int j = 0; j < 4; j++) {
        const int* lr = lrow + (size_t)(4 * t + j) * LOFFW + bin;
        st[j] = lr[0];
        v[j] = lr[1] - lr[0];
        sum += v[j];
    }
    int tot;
    int ex = block_excl_scan(sum, &tot);
    int run = ex;
    int* co = coffT + (size_t)bin * (NBK + 1);
    int* rs = rstartT + (size_t)bin * NBK;
#pragma unroll
    for (int j = 0; j < 4; j++) {
        co[4 * t + j] = run;
        rs[4 * t + j] = st[j];
        run += v[j];
    }
    if (t == 0) bintot[bin] = tot;
    if (t == 255) co[NBK] = run;
}

// ---------------- K2b: exclusive scan over bin totals -> binbase[CBIN+1] ----------------
__global__ void __launch_bounds__(256) bin_scan_bins(const int* __restrict__ bintot, int* __restrict__ binbase)
{
    int t = threadIdx.x;
    int i0 = 4 * t;
    int v0 = bintot[i0], v1 = bintot[i0 + 1], v2 = bintot[i0 + 2], v3 = bintot[i0 + 3];
    int ex = block_excl_scan(v0 + v1 + v2 + v3, nullptr);
    binbase[i0] = ex; binbase[i0 + 1] = ex + v0;
    binbase[i0 + 2] = ex + v0 + v1; binbase[i0 + 3] = ex + v0 + v1 + v2;
    if (t == 255) binbase[CBIN] = ex + v0 + v1 + v2 + v3;
}

// ---------------- K3: fused run-copy + per-bin counting sort over (node,srchalf) keys ----------------
// Serial per-thread run copy (compiler pipelines independent runs),
// LDS stageB scatter, coalesced global writeout. (Best of the three measured variants.)
__global__ void __launch_bounds__(256) bin_build(
    const int* __restrict__ schunk, const int* __restrict__ coffT, const int* __restrict__ rstartT,
    const int* __restrict__ binbase, int* __restrict__ binned, int* __restrict__ off2)
{
    __shared__ int stageA[SCAP];
    __shared__ int stageB[SCAP];
    __shared__ int cntS[NKEY];
    int bin = blockIdx.x, t = threadIdx.x;
    int beg = binbase[bin];
    int n = binbase[bin + 1] - beg; if (n > SCAP) n = SCAP;
    const int* co = coffT + (size_t)bin * (NBK + 1);
    const int* rs = rstartT + (size_t)bin * NBK;
    // gather this bin's 1024 runs from sorted chunks into stageA at deterministic offsets
    for (int c = t; c < NBK; c += 256) {
        int o = co[c], len = co[c + 1] - o;
        const int* sp = schunk + (size_t)c * EPB + rs[c];
        for (int j = 0; j < len; j++)
            if (o + j < SCAP) stageA[o + j] = sp[j];
    }
    cntS[t] = 0; cntS[t + 256] = 0;
    __syncthreads();
    for (int i = t; i < n; i += 256)
        atomicAdd(&cntS[stageA[i] & (NKEY - 1)], 1);
    __syncthreads();
    // scan over 512 keys: thread t owns keys 2t (half 0), 2t+1 (half 1)
    int v0 = cntS[2 * t], v1 = cntS[2 * t + 1];
    int ex = block_excl_scan(v0 + v1, nullptr);
    {
        long long node0 = (long long)bin * NPB + t;
        if (t < NPB && node0 <= NN) {
            off2[2 * node0] = beg + ex;
            if (node0 < NN) off2[2 * node0 + 1] = beg + ex + v0;
        }
    }
    cntS[2 * t] = ex; cntS[2 * t + 1] = ex + v0;
    __syncthreads();
    for (int i = t; i < n; i += 256) {
        int rec = stageA[i];
        int p = atomicAdd(&cntS[rec & (NKEY - 1)], 1);
        if (p < SCAP) stageB[p] = rec >> 9;
    }
    __syncthreads();
    for (int i = t; i < n; i += 256) binned[beg + i] = stageB[i];
}

// ---------------- Layer-1 node prep: h = x@W (bf16-packed row + fp32 asrc), self-loop init ----------------
__global__ void __launch_bounds__(256) node_prep1(
    const float* __restrict__ x, const float* __restrict__ W,
    const float* __restrict__ as_, const float* __restrict__ ad_,
    uint2* __restrict__ hq, float* __restrict__ adst,
    float* __restrict__ s, float* __restrict__ acc)
{
    __shared__ float sW[FIN * HD];
    __shared__ float sas[HD], sad[HD];
    for (int t = threadIdx.x; t < FIN * HD; t += 256) sW[t] = W[t];
    if (threadIdx.x < HD) { sas[threadIdx.x] = as_[threadIdx.x]; sad[threadIdx.x] = ad_[threadIdx.x]; }
    __syncthreads();
    int i = blockIdx.x * 256 + threadIdx.x;
    if (i >= NN) return;
    float xi[FIN];
    const float4* xp = reinterpret_cast<const float4*>(x + (size_t)i * FIN);
#pragma unroll
    for (int q = 0; q < 4; q++) { float4 v = xp[q]; xi[4*q] = v.x; xi[4*q+1] = v.y; xi[4*q+2] = v.z; xi[4*q+3] = v.w; }
    float hv[HD];
#pragma unroll
    for (int k = 0; k < HD; k++) {
        float a = 0.f;
#pragma unroll
        for (int j = 0; j < FIN; j++) a = fmaf(xi[j], sW[j * HD + k], a);
        hv[k] = a;
    }
    float sa = 0.f, sd = 0.f;
#pragma unroll
    for (int k = 0; k < HD; k++) { sa = fmaf(hv[k], sas[k], sa); sd = fmaf(hv[k], sad[k], sd); }
    float w = __expf(lrelu(sa + sd));   // self-loop weight (exact softmax max-shift cancellation)
    adst[i] = sd; s[i] = w;
    uint2* hp = hq + (size_t)i * 3;
    hp[0] = make_uint2(f2bf(hv[0]) | (f2bf(hv[1]) << 16), f2bf(hv[2]) | (f2bf(hv[3]) << 16));
    hp[1] = make_uint2(f2bf(hv[4]) | (f2bf(hv[5]) << 16), f2bf(hv[6]) | (f2bf(hv[7]) << 16));
    hp[2] = make_uint2(f2bf(hv[8]), __float_as_uint(sa));
#pragma unroll
    for (int k = 0; k < HD; k++) acc[(size_t)i*HD+k] = w * hv[k];
}

// ---------------- Layer-2 node prep: recompute y1, BN affine, h2 = y@W2 (bf16 pack) ----------------
__global__ void __launch_bounds__(256) node_prep2(
    const float* __restrict__ accin, const float* __restrict__ sin, const float* __restrict__ b,
    const float* __restrict__ sc, const float* __restrict__ sh,
    const float* __restrict__ W, const float* __restrict__ as_, const float* __restrict__ ad_,
    uint2* __restrict__ hq, float* __restrict__ adst,
    float* __restrict__ s, float* __restrict__ acc)
{
    __shared__ float sW[HD * HD];
    __shared__ float sas[HD], sad[HD], ssc[HD], ssh[HD], sb[HD];
    for (int t = threadIdx.x; t < HD * HD; t += 256) sW[t] = W[t];
    if (threadIdx.x < HD) {
        sas[threadIdx.x] = as_[threadIdx.x]; sad[threadIdx.x] = ad_[threadIdx.x];
        ssc[threadIdx.x] = sc[threadIdx.x]; ssh[threadIdx.x] = sh[threadIdx.x];
        sb[threadIdx.x] = b[threadIdx.x];
    }
    __syncthreads();
    int i = blockIdx.x * 256 + threadIdx.x;
    if (i >= NN) return;
    float inv = 1.0f / (sin[i] + 1e-16f);
    float xi[HD];
#pragma unroll
    for (int k = 0; k < HD; k++) {
        float v = fmaf(accin[(size_t)i*HD+k], inv, sb[k]);
        v = v > 0.f ? v : 0.f;
        xi[k] = fmaf(v, ssc[k], ssh[k]);
    }
    float hv[HD];
#pragma unroll
    for (int k = 0; k < HD; k++) {
        float a = 0.f;
#pragma unroll
        for (int j = 0; j < HD; j++) a = fmaf(xi[j], sW[j * HD + k], a);
        hv[k] = a;
    }
    float sa = 0.f, sd = 0.f;
#pragma unroll
    for (int k = 0; k < HD; k++) { sa = fmaf(hv[k], sas[k], sa); sd = fmaf(hv[k], sad[k], sd); }
    float w = __expf(lrelu(sa + sd));
    adst[i] = sd; s[i] = w;
    uint2* hp = hq + (size_t)i * 3;
    hp[0] = make_uint2(f2bf(hv[0]) | (f2bf(hv[1]) << 16), f2bf(hv[2]) | (f2bf(hv[3]) << 16));
    hp[1] = make_uint2(f2bf(hv[4]) | (f2bf(hv[5]) << 16), f2bf(hv[6]) | (f2bf(hv[7]) << 16));
    hp[2] = make_uint2(f2bf(hv[8]), __float_as_uint(sa));
#pragma unroll
    for (int k = 0; k < HD; k++) acc[(size_t)i*HD+k] = w * hv[k];
}

// ---------------- Gather pass (per src-half): 8 lanes/node, 2x-unrolled, register accumulate ----------------
#define ACCUM(w, A, B, C) \
    a[0] = fmaf(w, bf_lo(A.x), a[0]); a[1] = fmaf(w, bf_hi(A.x), a[1]); \
    a[2] = fmaf(w, bf_lo(A.y), a[2]); a[3] = fmaf(w, bf_hi(A.y), a[3]); \
    a[4] = fmaf(w, bf_lo(B.x), a[4]); a[5] = fmaf(w, bf_hi(B.x), a[5]); \
    a[6] = fmaf(w, bf_lo(B.y), a[6]); a[7] = fmaf(w, bf_hi(B.y), a[7]); \
    a[8] = fmaf(w, bf_lo(C.x), a[8]);

__global__ void __launch_bounds__(256) gat_gather(
    const int* __restrict__ off2, const int* __restrict__ esrc,
    const uint2* __restrict__ hq, const float* __restrict__ adst,
    float* __restrict__ s, float* __restrict__ acc, int half)
{
    int gidx = blockIdx.x * 32 + (threadIdx.x >> 3);
    int lane = threadIdx.x & 7;
    if (gidx >= NN) return;
    int beg = off2[2 * gidx + half], end = off2[2 * gidx + half + 1];
    float ad = adst[gidx];
    float wsum = 0.f;
    float a[HD];
#pragma unroll
    for (int k = 0; k < HD; k++) a[k] = 0.f;
    int e = beg + lane;
    for (; e + 8 < end; e += 16) {
        int s0 = esrc[e], s1 = esrc[e + 8];
        const uint2* p0 = hq + (size_t)s0 * 3;
        const uint2* p1 = hq + (size_t)s1 * 3;
        uint2 A0 = p0[0], B0 = p0[1], C0 = p0[2];
        uint2 A1 = p1[0], B1 = p1[1], C1 = p1[2];
        float w0 = __expf(lrelu(__uint_as_float(C0.y) + ad));
        float w1 = __expf(lrelu(__uint_as_float(C1.y) + ad));
        wsum += w0 + w1;
        ACCUM(w0, A0, B0, C0);
        ACCUM(w1, A1, B1, C1);
    }
    if (e < end) {
        int s0 = esrc[e];
        const uint2* p0 = hq + (size_t)s0 * 3;
        uint2 A0 = p0[0], B0 = p0[1], C0 = p0[2];
        float w0 = __expf(lrelu(__uint_as_float(C0.y) + ad));
        wsum += w0;
        ACCUM(w0, A0, B0, C0);
    }
#pragma unroll
    for (int o = 1; o < 8; o <<= 1) {
        wsum += __shfl_xor(wsum, o);
#pragma unroll
        for (int k = 0; k < HD; k++) a[k] += __shfl_xor(a[k], o);
    }
    if (lane == 0) {
        s[gidx] += wsum;
        float* ap = acc + (size_t)gidx * HD;
#pragma unroll
        for (int k = 0; k < HD; k++) ap[k] += a[k];
    }
}

// ---------------- Layer-1 finish: BN stats (hierarchical, staged atomics) ----------------
__global__ void __launch_bounds__(256) node_finish1(
    const float* __restrict__ acc, const float* __restrict__ s, const float* __restrict__ b,
    float* __restrict__ stage)
{
    int i = blockIdx.x * 256 + threadIdx.x;
    bool act = i < NN;
    float inv = act ? 1.0f / (s[i] + 1e-16f) : 0.f;
    float y[HD];
#pragma unroll
    for (int k = 0; k < HD; k++) {
        float v = act ? fmaf(acc[(size_t)i*HD+k], inv, __ldg(&b[k])) : 0.f;
        y[k] = v > 0.f ? v : 0.f;
    }
    __shared__ float red[4][2 * HD];
    int lane = threadIdx.x & 63, wv = threadIdx.x >> 6;
#pragma unroll
    for (int k = 0; k < HD; k++) {
        float sm = y[k], sq = y[k] * y[k];
#pragma unroll
        for (int o = 32; o > 0; o >>= 1) { sm += __shfl_down(sm, o); sq += __shfl_down(sq, o); }
        if (lane == 0) { red[wv][k] = sm; red[wv][HD + k] = sq; }
    }
    __syncthreads();
    int t = threadIdx.x;
    if (t < 2 * HD) {
        float v = red[0][t] + red[1][t] + red[2][t] + red[3][t];
        atomicAdd(&stage[(blockIdx.x & (NSTAGE - 1)) * 2 * HD + t], v);
    }
}

// ---------------- Layer-2 finish: BN stats (staged) + wave-segmented pooling ----------------
__global__ void __launch_bounds__(256) node_finish2(
    const float* __restrict__ acc, const float* __restrict__ s, const float* __restrict__ b,
    const int* __restrict__ batch,
    float* __restrict__ stage,
    float* __restrict__ pool, float* __restrict__ cnt)
{
    int i = blockIdx.x * 256 + threadIdx.x;
    bool act = i < NN;
    float inv = act ? 1.0f / (s[i] + 1e-16f) : 0.f;
    float y[HD];
#pragma unroll
    for (int k = 0; k < HD; k++) {
        float v = act ? fmaf(acc[(size_t)i*HD+k], inv, __ldg(&b[k])) : 0.f;
        y[k] = v > 0.f ? v : 0.f;
    }
    __shared__ float red[4][2 * HD];
    int lane = threadIdx.x & 63, wv = threadIdx.x >> 6;
#pragma unroll
    for (int k = 0; k < HD; k++) {
        float sm = y[k], sq = y[k] * y[k];
#pragma unroll
        for (int o = 32; o > 0; o >>= 1) { sm += __shfl_down(sm, o); sq += __shfl_down(sq, o); }
        if (lane == 0) { red[wv][k] = sm; red[wv][HD + k] = sq; }
    }
    __syncthreads();
    int t = threadIdx.x;
    if (t < 2 * HD) {
        float v = red[0][t] + red[1][t] + red[2][t] + red[3][t];
        atomicAdd(&stage[(blockIdx.x & (NSTAGE - 1)) * 2 * HD + t], v);
    }
    // Wave-segmented pooling: one iteration per distinct graph in the wave.
    int g = act ? batch[i] : -1;
    unsigned long long alive = __ballot(g >= 0);
    while (alive) {
        int leader = (int)__builtin_ctzll(alive);
        int g0 = __shfl(g, leader);
        bool mine = (g == g0);
#pragma unroll
        for (int k = 0; k < HD; k++) {
            float v = mine ? y[k] : 0.f;
#pragma unroll
            for (int o = 32; o > 0; o >>= 1) v += __shfl_xor(v, o);
            if (lane == leader) atomicAdd(&pool[g0 * HD + k], v);
        }
        float c = mine ? 1.f : 0.f;
#pragma unroll
        for (int o = 32; o > 0; o >>= 1) c += __shfl_xor(c, o);
        if (lane == leader) atomicAdd(&cnt[g0], c);
        alive &= ~__ballot(mine);
    }
}

// ---------------- BN stat finalize ----------------
__global__ void bn_finalize(const float* __restrict__ stage,
                            const float* __restrict__ gamma, const float* __restrict__ beta,
                            float* __restrict__ scale, float* __restrict__ shift)
{
    __shared__ float tot[2 * HD];
    int t = threadIdx.x;
    if (t < 2 * HD) {
        float v = 0.f;
        for (int j = 0; j < NSTAGE; j++) v += stage[j * 2 * HD + t];
        tot[t] = v;
    }
    __syncthreads();
    if (t < HD) {
        float mu = tot[t] * (1.0f / NN);
        float var = tot[HD + t] * (1.0f / NN) - mu * mu;
        float rstd = rsqrtf(var + 1e-5f);
        float sc = gamma[t] * rstd;
        scale[t] = sc;
        shift[t] = beta[t] - mu * sc;
    }
}

// ---------------- Final: per-graph BN-affine + 4-layer linear MLP ----------------
__global__ void __launch_bounds__(256) final_mlp(
    const float* __restrict__ pool, const float* __restrict__ cnt,
    const float* __restrict__ sc, const float* __restrict__ sh,
    const float* __restrict__ mW1, const float* __restrict__ mb1,
    const float* __restrict__ mW2, const float* __restrict__ mb2,
    const float* __restrict__ mW3, const float* __restrict__ mb3,
    const float* __restrict__ mW4, const float* __restrict__ mb4,
    float* __restrict__ out)
{
    __shared__ float w1[81], w2[81], w3[81], bb1[9], bb2[9], bb3[9], w4[9], ssc[9], ssh[9];
    int t = threadIdx.x;
    if (t < 81) { w1[t] = mW1[t]; w2[t] = mW2[t]; w3[t] = mW3[t]; }
    if (t < 9) {
        bb1[t] = mb1[t]; bb2[t] = mb2[t]; bb3[t] = mb3[t];
        w4[t] = mW4[t]; ssc[t] = sc[t]; ssh[t] = sh[t];
    }
    __syncthreads();
    int g = blockIdx.x * 256 + t;
    if (g >= NG) return;
    float c = cnt[g];
    float p[9], q[9];
#pragma unroll
    for (int k = 0; k < 9; k++) p[k] = fmaf(ssc[k], pool[g * 9 + k], ssh[k] * c);
#pragma unroll
    for (int k = 0; k < 9; k++) {
        float a = bb1[k];
#pragma unroll
        for (int j = 0; j < 9; j++) a = fmaf(p[j], w1[j * 9 + k], a);
        q[k] = a;
    }
#pragma unroll
    for (int k = 0; k < 9; k++) {
        float a = bb2[k];
#pragma unroll
        for (int j = 0; j < 9; j++) a = fmaf(q[j], w2[j * 9 + k], a);
        p[k] = a;
    }
#pragma unroll
    for (int k = 0; k < 9; k++) {
        float a = bb3[k];
#pragma unroll
        for (int j = 0; j < 9; j++) a = fmaf(p[j], w3[j * 9 + k], a);
        q[k] = a;
    }
    float o = mb4[0];
#pragma unroll
    for (int j = 0; j < 9; j++) o = fmaf(q[j], w4[j], o);
    out[g] = o;
}

extern "C" void kernel_launch(void* const* d_in, const int* in_sizes, int n_in,
                              void* d_out, int out_size, void* d_ws, size_t ws_size,
                              hipStream_t stream)
{
    const float* x   = (const float*)d_in[0];
    const int*   ei  = (const int*)d_in[1];
    const int*   bat = (const int*)d_in[2];
    const float* W1  = (const float*)d_in[3];
    const float* as1 = (const float*)d_in[4];
    const float* ad1 = (const float*)d_in[5];
    const float* b1  = (const float*)d_in[6];
    const float* g1  = (const float*)d_in[7];
    const float* be1 = (const float*)d_in[8];
    const float* W2  = (const float*)d_in[9];
    const float* as2 = (const float*)d_in[10];
    const float* ad2 = (const float*)d_in[11];
    const float* b2  = (const float*)d_in[12];
    const float* g2  = (const float*)d_in[13];
    const float* be2 = (const float*)d_in[14];
    const float* mW1 = (const float*)d_in[15];
    const float* mb1 = (const float*)d_in[16];
    const float* mW2 = (const float*)d_in[17];
    const float* mb2 = (const float*)d_in[18];
    const float* mW3 = (const float*)d_in[19];
    const float* mb3 = (const float*)d_in[20];
    const float* mW4 = (const float*)d_in[21];
    const float* mb4 = (const float*)d_in[22];
    float* out = (float*)d_out;

    // -------- workspace layout (build-time buffers overlaid with layer-time buffers) --------
    float* ws   = (float*)d_ws;
    float* zb   = ws;                          // zeroed block (small, persistent)
    float* stg1 = zb;                          // 64*18
    float* stg2 = stg1 + NSTAGE * 2 * HD;      // 64*18
    float* pool = stg2 + NSTAGE * 2 * HD;      // G*9
    float* cnt  = pool + (size_t)NG * HD;      // G
    float* sc1  = cnt + NG;                    // 9
    float* sh1  = sc1 + HD;                    // 9
    float* sc2  = sh1 + HD;                    // 9
    float* sh2  = sc2 + HD;                    // 9
    int*   off2   = (int*)(sh2 + HD);          // 2*NN+1 (per-(node,srchalf) offsets)
    int*   binned = off2 + (2 * NN + 1);       // NE (node-half-sorted esrc)
    int*   uni    = binned + NE;               // union region: schunk (NE ints) | {hq,adst,s,acc}
    int*   schunk = uni;                       // NE ints (sorted chunks; dead after bin_build)
    uint2* hq     = (uint2*)uni;               // NN rows x 24B = 1.5M words (overlays schunk)
    float* adst   = (float*)uni + (size_t)NN * 6;  // N
    float* s      = adst + NN;                 // N
    float* acc    = s + NN;                    // N*9  (total 4.25M words < NE=8M ✓)
    int*   lrow    = uni + NE;                 // NBK*LOFFW
    int*   coffT   = lrow + (size_t)NBK * LOFFW;        // CBIN*(NBK+1) row-major
    int*   rstartT = coffT + (size_t)CBIN * (NBK + 1);  // CBIN*NBK row-major
    int*   bintot  = rstartT + (size_t)CBIN * NBK;      // CBIN
    int*   binbase = bintot + CBIN;            // CBIN+1

    size_t zbytes = (size_t)(2 * NSTAGE * 2 * HD + NG * HD + NG + 4 * HD) * sizeof(float);
    hipMemsetAsync(zb, 0, zbytes, stream);

    const int* srcs = ei;
    const int* dsts = ei + NE;
    int nb  = (NN + 255) / 256;
    int ngb = (NN + 31) / 32;

    // CSR build: LDS chunk sort -> scans (row-major metadata) -> fused run-copy + (node,half) sort
    chunk_sort<<<NBK, 256, 0, stream>>>(srcs, dsts, schunk, lrow);
    bin_scan_chunks<<<CBIN, 256, 0, stream>>>(lrow, coffT, rstartT, bintot);
    bin_scan_bins<<<1, 256, 0, stream>>>(bintot, binbase);
    bin_build<<<CBIN, 256, 0, stream>>>(schunk, coffT, rstartT, binbase, binned, off2);

    // Layer 1 (hq overwrites dead schunk region); two gather passes, each an L2-resident hq slice
    node_prep1<<<nb, 256, 0, stream>>>(x, W1, as1, ad1, hq, adst, s, acc);
    gat_gather<<<ngb, 256, 0, stream>>>(off2, binned, hq, adst, s, acc, 0);
    gat_gather<<<ngb, 256, 0, stream>>>(off2, binned, hq, adst, s, acc, 1);
    node_finish1<<<nb, 256, 0, stream>>>(acc, s, b1, stg1);
    bn_finalize<<<1, 64, 0, stream>>>(stg1, g1, be1, sc1, sh1);

    // Layer 2
    node_prep2<<<nb, 256, 0, stream>>>(acc, s, b1, sc1, sh1, W2, as2, ad2, hq, adst, s, acc);
    gat_gather<<<ngb, 256, 0, stream>>>(off2, binned, hq, adst, s, acc, 0);
    gat_gather<<<ngb, 256, 0, stream>>>(off2, binned, hq, adst, s, acc, 1);
    node_finish2<<<nb, 256, 0, stream>>>(acc, s, b2, bat, stg2, pool, cnt);
    bn_finalize<<<1, 64, 0, stream>>>(stg2, g2, be2, sc2, sh2);

    final_mlp<<<(NG + 255) / 256, 256, 0, stream>>>(pool, cnt, sc2, sh2,
                                                    mW1, mb1, mW2, mb2, mW3, mb3, mW4, mb4, out);
}